// Round 8
// baseline (360.784 us; speedup 1.0000x reference)
//
#include <hip/hip_runtime.h>

// ---------- types ----------
typedef float  f32x4 __attribute__((ext_vector_type(4)));
typedef short  s16x8 __attribute__((ext_vector_type(8)));
typedef __bf16 b16x8 __attribute__((ext_vector_type(8)));

#define DEV __device__ __forceinline__

DEV unsigned short f2b(float f) {           // fp32 -> bf16 RNE
  unsigned u = __builtin_bit_cast(unsigned, f);
  u = (u + 0x7FFFu + ((u >> 16) & 1u)) >> 16;
  return (unsigned short)u;
}
DEV b16x8 ld8(const unsigned short* p) {    // 16B fragment load + reinterpret
  return __builtin_bit_cast(b16x8, *(const s16x8*)p);
}
DEV float sigm(float x) { return __builtin_amdgcn_rcpf(1.f + __expf(-x)); }
DEV float tanh_fast(float x) {
  float e = __expf(2.f * x);                // overflow-safe: e=inf -> 1, e=0 -> -1
  return 1.f - 2.f * __builtin_amdgcn_rcpf(e + 1.f);
}
DEV f32x4 mfma_bf16(b16x8 a, b16x8 b, f32x4 c) {
  return __builtin_amdgcn_mfma_f32_16x16x32_bf16(a, b, c, 0, 0, 0);
}

// ---------- prep: all fp32->bf16 weight conversion + Waug build + out prefill ----
// Waug [768][288] = [Whh k-permuted | Wih | bias@271 | 0].
struct PrepArgs {
  const float *whh[2], *wih[2], *bih[2], *bhh[2];
  const float *src[2][4];               // fc1..fc4 fp32 weights per branch
  unsigned short *waug[2], *dst[2][4];  // bf16 outputs
  const float *qb[2];
  float *out;                           // prefill with qb (fc4q atomically adds)
};

__global__ __launch_bounds__(256) void prep_kernel(PrepArgs p) {
  const int job = blockIdx.y;
  const int i0 = blockIdx.x * 256 + threadIdx.x;
  const int stride = gridDim.x * 256;
  if (job < 2) {
    const float* whh = p.whh[job];
    const float* wih = p.wih[job];
    const float* bih = p.bih[job];
    const float* bhh = p.bhh[job];
    unsigned short* dst = p.waug[job];
    for (int idx = i0; idx < 768 * 288; idx += stride) {
      int j = idx / 288, k = idx - j * 288;
      float v = 0.f;
      if (k < 256) {
        int o = k & 31;
        int kk = (k & 0x1E0) + (o >> 1) + ((o & 1) << 4);   // inverse pair-perm
        v = whh[j * 256 + kk];
      } else if (k < 271)  v = wih[j * 15 + (k - 256)];
      else if (k == 271)   v = (j < 512) ? (bih[j] + bhh[j]) : bih[j];
      dst[idx] = f2b(v);
    }
  } else if (job < 10) {
    const int jj = job - 2, br = jj >> 2, ly = jj & 3;
    const int rowsA[4] = {1024, 1024, 512, 256};
    const int scA[4]   = {272, 1024, 1024, 512};
    const int dcA[4]   = {320, 1024, 1024, 512};   // fc1 K padded to 320
    const float* src = p.src[br][ly];
    unsigned short* dst = p.dst[br][ly];
    const int sc = scA[ly], dc = dcA[ly], tot = rowsA[ly] * dc;
    for (int idx = i0; idx < tot; idx += stride) {
      int r = idx / dc, c = idx - r * dc;
      float v = (c < sc) ? src[r * sc + c] : 0.f;
      dst[idx] = f2b(v);
    }
  } else {
    for (int idx = i0; idx < 4096; idx += stride)
      p.out[idx] = p.qb[idx >> 11][0];
  }
}

// ---------- persistent fused GRU (R7 structure + reordered arena phase) ----------
// 256 blocks x 256 thr; wave w owns 12 col-tiles gate*256+64w+16j.
// h-ksteps 0..6 in regs (336 VGPR incl. AGPR backing); k7 + aug in LDS arenas.
// Order per step: k0..6 (register MFMAs, covers arena-read latency) -> k7 ->
// aug last (n-gate aug into separate accNa so i_n snapshot stays exact).
#define GRU_LDS_BYTES 147584
__attribute__((amdgpu_waves_per_eu(1, 1)))
__global__ void __launch_bounds__(256) gru_kernel(
    const float* __restrict__ state, const float* __restrict__ action,
    const int* __restrict__ lengths,
    const unsigned short* __restrict__ waug0, const unsigned short* __restrict__ waug1,
    const float* __restrict__ bhh0, const float* __restrict__ bhh1,
    unsigned short* __restrict__ x0, unsigned short* __restrict__ x1) {
  extern __shared__ char smem[];
  unsigned short* W7   = (unsigned short*)smem;             // 49152 B: kstep7 frags
  unsigned short* WA   = (unsigned short*)(smem + 49152);   // 49152 B: aug frags
  unsigned short* SgL  = (unsigned short*)(smem + 98304);   // 32768 B: state A-frags
  unsigned*       Hb2  = (unsigned*)(smem + 131072);        // 16384 B: 2x16x128 dw
  int* lenS = (int*)(smem + 147456);
  int* mlS  = (int*)(smem + 147520);

  const int tid = threadIdx.x;
  const int lane = tid & 63, w = tid >> 6;   // 4 waves
  const int l15 = lane & 15, q = lane >> 4;
  const int g = blockIdx.x & 1;
  const int r0 = (blockIdx.x >> 1) * 16;

  const unsigned short* Waug = g ? waug1 : waug0;
  const float* bhh = g ? bhh1 : bhh0;
  unsigned short* xout = g ? x1 : x0;

  // ---- phase a: zero Hb, load lens, build SgL aug A-frags from global ----
  for (int i = tid; i < 4096; i += 256) Hb2[i] = 0;
  if (tid < 16) lenS[tid] = lengths[r0 + tid];
  for (int s = tid; s < 64 * 32; s += 256) {
    const int t = s >> 5, L = s & 31;
    const int q2 = L >> 4, r = L & 15;
    const float* sp = state + (size_t)(r0 + r) * 960 + t * 15;
    s16x8 h;
#pragma unroll
    for (int j = 0; j < 8; j++) {
      const int k = q2 * 8 + j;
      float v = (k < 15) ? sp[k] : (k == 15 ? 1.0f : 0.f);
      h[j] = (short)f2b(v);
    }
    *(s16x8*)(SgL + (size_t)s * 8) = h;
  }
  __syncthreads();
  if (tid == 0) {
    int m = 1;
    for (int i = 0; i < 16; i++) m = lenS[i] > m ? lenS[i] : m;
    *mlS = m;
  }

  // ---- phase c: weights -> regs (k0..6) + arenas (aug, k7) ----
  int c0[12];
#pragma unroll
  for (int gate = 0; gate < 3; gate++)
#pragma unroll
    for (int j = 0; j < 4; j++) c0[gate * 4 + j] = gate * 256 + 64 * w + 16 * j;

  b16x8 wres[12][7];
#pragma unroll
  for (int i = 0; i < 12; i++) {
    const unsigned short* bpi = Waug + (size_t)(c0[i] + l15) * 288 + q * 8;
#pragma unroll
    for (int j = 0; j < 7; j++) wres[i][j] = ld8(bpi + j * 32);
    *(s16x8*)(W7 + ((size_t)i * 256 + tid) * 8) =
        __builtin_bit_cast(s16x8, ld8(bpi + 7 * 32));
    *(s16x8*)(WA + ((size_t)i * 256 + tid) * 8) =
        __builtin_bit_cast(s16x8, ld8(bpi + 256));
  }
  float bnH[4];
#pragma unroll
  for (int j = 0; j < 4; j++) bnH[j] = bhh[c0[8 + j] + l15];
  int len4[4];
#pragma unroll
  for (int r = 0; r < 4; r++) len4[r] = lenS[q * 4 + r];

  int aOff[8];
#pragma unroll
  for (int k = 0; k < 8; k++) {
    const int ck = 4 * k + q;
    const int pk = (ck & 24) | ((ck & 7) ^ (l15 & 7));
    aOff[k] = l15 * 128 + pk * 4;
  }
  int wOff[2][4];
#pragma unroll
  for (int p = 0; p < 2; p++)
#pragma unroll
    for (int rg = 0; rg < 4; rg++) {
      const int row = q * 4 + rg;
      const int cb = 8 * w + 4 * p + (l15 >> 2);
      const int pw = (cb & 24) | ((cb & 7) ^ (row & 7));
      wOff[p][rg] = row * 128 + pw * 4 + (l15 & 3);
    }
  __syncthreads();
  const int maxlen = *mlS;

  float hold[4][4] = {{0,0,0,0},{0,0,0,0},{0,0,0,0},{0,0,0,0}};
  int poff = 0;

  for (int t = 0; t < maxlen; ++t) {
    __syncthreads();  // prev step's writes to buffer poff complete

    f32x4 acc[12];
#pragma unroll
    for (int i = 0; i < 12; i++) acc[i] = f32x4{0.f, 0.f, 0.f, 0.f};

    const unsigned* hb = Hb2 + poff;
    // issue aug A-read early; consumed at the end of the step
    b16x8 a8 = ld8(SgL + t * 256 + ((q & 1) * 16 + l15) * 8);

    // h ksteps 0..6 from registers — long MFMA stretch, covers arena reads
#pragma unroll
    for (int k = 0; k < 7; k++) {
      b16x8 a = __builtin_bit_cast(b16x8, *(const uint4*)(hb + aOff[k]));
#pragma unroll
      for (int i = 0; i < 12; i++) acc[i] = mfma_bf16(a, wres[i][k], acc[i]);
    }
    // kstep 7 from W7 arena
    {
      b16x8 a = __builtin_bit_cast(b16x8, *(const uint4*)(hb + aOff[7]));
#pragma unroll
      for (int i = 0; i < 12; i++) {
        b16x8 bw = ld8(W7 + ((size_t)i * 256 + tid) * 8);
        acc[i] = mfma_bf16(a, bw, acc[i]);
      }
    }
    // aug kstep LAST: r,z tiles into acc; n tiles into separate accNa (=i_n)
    f32x4 accNa[4];
#pragma unroll
    for (int i = 0; i < 8; i++) {
      b16x8 bw = ld8(WA + ((size_t)i * 256 + tid) * 8);
      acc[i] = mfma_bf16(a8, bw, acc[i]);
    }
#pragma unroll
    for (int j = 0; j < 4; j++) {
      b16x8 bw = ld8(WA + ((size_t)(8 + j) * 256 + tid) * 8);
      accNa[j] = mfma_bf16(a8, bw, f32x4{0.f, 0.f, 0.f, 0.f});
    }

    // elementwise + packed write to the OTHER buffer (no second barrier)
    unsigned* hbw = Hb2 + (poff ^ 2048);
#pragma unroll
    for (int j = 0; j < 4; j++)
#pragma unroll
      for (int rg = 0; rg < 4; rg++) {
        const bool live = (t < len4[rg]);
        float inn = accNa[j][rg];                 // i_n (incl. bih fold)
        float hn = acc[8 + j][rg] + bnH[j];       // h@Whh_n + bhh_n
        float r = sigm(acc[j][rg]);
        float z = sigm(acc[4 + j][rg]);
        float n = tanh_fast(inn + r * hn);
        float h = n + z * (hold[j][rg] - n);
        h = live ? h : hold[j][rg];
        hold[j][rg] = h;
      }
#pragma unroll
    for (int p = 0; p < 2; p++)
#pragma unroll
      for (int rg = 0; rg < 4; rg++)
        hbw[wOff[p][rg]] = (unsigned)f2b(hold[2 * p][rg]) |
                           ((unsigned)f2b(hold[2 * p + 1][rg]) << 16);
    poff ^= 2048;
  }

  // emit x = [state[:,0,:], action, h, 0-pad] bf16 [16][320]
#pragma unroll
  for (int j = 0; j < 4; j++)
#pragma unroll
    for (int rg = 0; rg < 4; rg++) {
      const int row = q * 4 + rg;
      xout[(size_t)(r0 + row) * 320 + 16 + c0[j] + l15] = f2b(hold[j][rg]);
    }
  for (int s = tid; s < 1024; s += 256) {
    const int row = s >> 6, cc = s & 63;
    float v; int col;
    if (cc < 15)       { v = state[(size_t)(r0 + row) * 960 + cc]; col = cc; }
    else if (cc == 15) { v = action[r0 + row]; col = 15; }
    else               { v = 0.f; col = 256 + cc; }  // 272..319 zero pad
    xout[(size_t)(r0 + row) * 320 + col] = f2b(v);
  }
}

// ---------- bf16 GEMM, reg-staged double-buffer, BK=64, ONE barrier/iter ----
// 64x64 tile, 256 thr (2x2 waves). Global loads for iter k+1 issue before the
// barrier (VGPR dest — no LDS ordering), ds_write goes to the alternate
// buffer, so latency overlaps MFMA+ds_read. 32 KB LDS -> 4 blocks/CU.
DEV int slotOf(int c) { return (c & ~7) | ((c & 7) ^ ((c >> 3) & 7)); }

__global__ __launch_bounds__(256, 4) void gemm_dbuf(
    const unsigned short* __restrict__ A0, const unsigned short* __restrict__ A1,
    const unsigned short* __restrict__ W0, const unsigned short* __restrict__ W1,
    const float* __restrict__ b0, const float* __restrict__ b1,
    unsigned short* __restrict__ Y0, unsigned short* __restrict__ Y1,
    int N, int K) {
  const unsigned short* A = blockIdx.z ? A1 : A0;
  const unsigned short* W = blockIdx.z ? W1 : W0;
  const float* bias = blockIdx.z ? b1 : b0;
  unsigned short* Y = blockIdx.z ? Y1 : Y0;

  const int tid = threadIdx.x;
  const int lane = tid & 63, wid = tid >> 6;
  const int wm = wid >> 1, wn = wid & 1;
  const int l15 = lane & 15, q = lane >> 4;
  const int m0 = blockIdx.x * 64, n0 = blockIdx.y * 64;

  __shared__ unsigned short As[2][4096];
  __shared__ unsigned short Bs[2][4096];

  f32x4 acc[2][2];
#pragma unroll
  for (int mi = 0; mi < 2; mi++)
#pragma unroll
    for (int ni = 0; ni < 2; ni++) acc[mi][ni] = f32x4{0.f, 0.f, 0.f, 0.f};

  // staging chunks: 512 16B chunks per matrix; thread owns 2 of each
  const int c0c = tid * 2, c1c = tid * 2 + 1;
  const int ar0 = c0c >> 3, ak0 = (c0c & 7) * 8;
  const int ar1 = c1c >> 3, ak1 = (c1c & 7) * 8;
  const int ws0 = slotOf(c0c) * 8, ws1 = slotOf(c1c) * 8;
  const unsigned short* pa0 = A + (size_t)(m0 + ar0) * K + ak0;
  const unsigned short* pa1 = A + (size_t)(m0 + ar1) * K + ak1;
  const unsigned short* pb0 = W + (size_t)(n0 + ar0) * K + ak0;
  const unsigned short* pb1 = W + (size_t)(n0 + ar1) * K + ak1;

  const int niter = K >> 6;
  s16x8 ra0 = *(const s16x8*)pa0, ra1 = *(const s16x8*)pa1;
  s16x8 rb0 = *(const s16x8*)pb0, rb1 = *(const s16x8*)pb1;
  *(s16x8*)&As[0][ws0] = ra0; *(s16x8*)&As[0][ws1] = ra1;
  *(s16x8*)&Bs[0][ws0] = rb0; *(s16x8*)&Bs[0][ws1] = rb1;

  for (int it = 0; it < niter; ++it) {
    const unsigned short* as = As[it & 1];
    const unsigned short* bs = Bs[it & 1];
    const bool pf = (it + 1 < niter);
    if (pf) {
      const int k0 = (it + 1) << 6;
      ra0 = *(const s16x8*)(pa0 + k0); ra1 = *(const s16x8*)(pa1 + k0);
      rb0 = *(const s16x8*)(pb0 + k0); rb1 = *(const s16x8*)(pb1 + k0);
    }
    __syncthreads();   // buf[it&1] writes visible to all waves

#pragma unroll
    for (int s = 0; s < 2; s++) {
      b16x8 af[2], bf[2];
#pragma unroll
      for (int mi = 0; mi < 2; mi++) {
        const int ml = wm * 32 + mi * 16 + l15;
        af[mi] = ld8(as + slotOf(ml * 8 + s * 4 + q) * 8);
      }
#pragma unroll
      for (int ni = 0; ni < 2; ni++) {
        const int nl = wn * 32 + ni * 16 + l15;
        bf[ni] = ld8(bs + slotOf(nl * 8 + s * 4 + q) * 8);
      }
#pragma unroll
      for (int mi = 0; mi < 2; mi++)
#pragma unroll
        for (int ni = 0; ni < 2; ni++)
          acc[mi][ni] = mfma_bf16(af[mi], bf[ni], acc[mi][ni]);
    }
    if (pf) {
      const int nb = (it + 1) & 1;
      *(s16x8*)&As[nb][ws0] = ra0; *(s16x8*)&As[nb][ws1] = ra1;
      *(s16x8*)&Bs[nb][ws0] = rb0; *(s16x8*)&Bs[nb][ws1] = rb1;
    }
  }

#pragma unroll
  for (int ni = 0; ni < 2; ni++) {
    const int col = n0 + wn * 32 + ni * 16 + l15;
    const float bv = bias[col];
#pragma unroll
    for (int mi = 0; mi < 2; mi++) {
      const int rbase = m0 + wm * 32 + mi * 16 + q * 4;
#pragma unroll
      for (int rg = 0; rg < 4; rg++) {
        float v = acc[mi][ni][rg] + bv;
        v = fmaxf(v, 0.f);
        Y[(size_t)(rbase + rg) * N + col] = f2b(v);
      }
    }
  }
}

// ---------- fc4 + q fused: out[b] += qw . relu(y3[b] @ W4^T + b4) ----------
DEV void async16(const unsigned short* g, unsigned short* l) {
  __builtin_amdgcn_global_load_lds(
      (const __attribute__((address_space(1))) unsigned int*)g,
      (__attribute__((address_space(3))) unsigned int*)l, 16, 0, 0);
}

__global__ __launch_bounds__(256, 4) void fc4q_kernel(
    const unsigned short* __restrict__ A0, const unsigned short* __restrict__ A1,
    const unsigned short* __restrict__ W0, const unsigned short* __restrict__ W1,
    const float* __restrict__ b0, const float* __restrict__ b1,
    const float* __restrict__ qw0, const float* __restrict__ qw1,
    float* __restrict__ out) {
  const unsigned short* A = blockIdx.z ? A1 : A0;
  const unsigned short* W = blockIdx.z ? W1 : W0;
  const float* bias = blockIdx.z ? b1 : b0;
  const float* qw = blockIdx.z ? qw1 : qw0;

  const int tid = threadIdx.x;
  const int lane = tid & 63, wn = tid >> 6;
  const int l15 = lane & 15, q = lane >> 4;
  const int m0 = blockIdx.x * 32;
  const int nbase = blockIdx.y * 128;
  const int K = 512;

  __shared__ unsigned short As[32 * 32];
  __shared__ unsigned short Bs[128 * 32];
  __shared__ float red[32][4];

  f32x4 acc[2][2];
#pragma unroll
  for (int mi = 0; mi < 2; mi++)
#pragma unroll
    for (int ni = 0; ni < 2; ni++) acc[mi][ni] = f32x4{0.f, 0.f, 0.f, 0.f};

  const int srow = tid >> 2, scol = (tid & 3) * 8;
  for (int k0 = 0; k0 < K; k0 += 32) {
    if (tid < 128)
      async16(A + (size_t)(m0 + srow) * K + scol + k0, &As[tid * 8]);
#pragma unroll
    for (int g64 = 0; g64 < 2; g64++)
      async16(W + (size_t)(nbase + g64 * 64 + srow) * K + scol + k0,
              &Bs[g64 * 2048 + tid * 8]);
    __syncthreads();

    b16x8 af[2], bf[2];
#pragma unroll
    for (int mi = 0; mi < 2; mi++)
      af[mi] = ld8(&As[(mi * 16 + l15) * 32 + q * 8]);
#pragma unroll
    for (int ni = 0; ni < 2; ni++)
      bf[ni] = ld8(&Bs[(wn * 32 + ni * 16 + l15) * 32 + q * 8]);
#pragma unroll
    for (int mi = 0; mi < 2; mi++)
#pragma unroll
      for (int ni = 0; ni < 2; ni++)
        acc[mi][ni] = mfma_bf16(af[mi], bf[ni], acc[mi][ni]);
    __syncthreads();
  }

#pragma unroll
  for (int mi = 0; mi < 2; mi++) {
#pragma unroll
    for (int rg = 0; rg < 4; rg++) {
      float s = 0.f;
#pragma unroll
      for (int ni = 0; ni < 2; ni++) {
        const int col = nbase + wn * 32 + ni * 16 + l15;
        float v = fmaxf(acc[mi][ni][rg] + bias[col], 0.f);
        s += v * qw[col];
      }
#pragma unroll
      for (int off = 1; off < 16; off <<= 1) s += __shfl_xor(s, off);
      if (l15 == 0) red[mi * 16 + q * 4 + rg][wn] = s;
    }
  }
  __syncthreads();
  if (tid < 32) {
    float t = red[tid][0] + red[tid][1] + red[tid][2] + red[tid][3];
    atomicAdd(out + (size_t)blockIdx.z * 2048 + m0 + tid, t);
  }
}

// ---------- host ----------
extern "C" void kernel_launch(void* const* d_in, const int* in_sizes, int n_in,
                              void* d_out, int out_size, void* d_ws, size_t ws_size,
                              hipStream_t stream) {
  const float* state   = (const float*)d_in[0];
  const float* action  = (const float*)d_in[1];
  const int*   lengths = (const int*)d_in[2];
  const float* g_wih[2] = {(const float*)d_in[3], (const float*)d_in[17]};
  const float* g_whh[2] = {(const float*)d_in[4], (const float*)d_in[18]};
  const float* g_bih[2] = {(const float*)d_in[5], (const float*)d_in[19]};
  const float* g_bhh[2] = {(const float*)d_in[6], (const float*)d_in[20]};
  const float* fcw[2][4] = {
      {(const float*)d_in[7], (const float*)d_in[9], (const float*)d_in[11], (const float*)d_in[13]},
      {(const float*)d_in[21], (const float*)d_in[23], (const float*)d_in[25], (const float*)d_in[27]}};
  const float* fcb[2][4] = {
      {(const float*)d_in[8], (const float*)d_in[10], (const float*)d_in[12], (const float*)d_in[14]},
      {(const float*)d_in[22], (const float*)d_in[24], (const float*)d_in[26], (const float*)d_in[28]}};
  const float* qw[2] = {(const float*)d_in[15], (const float*)d_in[29]};
  const float* qb[2] = {(const float*)d_in[16], (const float*)d_in[30]};
  float* out = (float*)d_out;

  uintptr_t base = (uintptr_t)d_ws;
  auto alloc = [&](size_t bytes) -> unsigned short* {
    void* p = (void*)base;
    base += (bytes + 255) & ~(size_t)255;
    return (unsigned short*)p;
  };
  unsigned short *waug[2], *w1b[2], *w2b[2], *w3b[2], *w4b[2], *xb[2], *yA[2], *yB[2];
  for (int g = 0; g < 2; g++) waug[g] = alloc(768 * 288 * 2);
  for (int g = 0; g < 2; g++) w1b[g] = alloc(1024 * 320 * 2);
  for (int g = 0; g < 2; g++) w2b[g] = alloc(1024 * 1024 * 2);
  for (int g = 0; g < 2; g++) w3b[g] = alloc(512 * 1024 * 2);
  for (int g = 0; g < 2; g++) w4b[g] = alloc(256 * 512 * 2);
  for (int g = 0; g < 2; g++) xb[g] = alloc(2048 * 320 * 2);
  for (int g = 0; g < 2; g++) yA[g] = alloc(2048 * 1024 * 2);
  for (int g = 0; g < 2; g++) yB[g] = alloc(2048 * 1024 * 2);
  (void)ws_size; (void)in_sizes; (void)n_in; (void)out_size;

  PrepArgs pa;
  for (int g = 0; g < 2; g++) {
    pa.whh[g] = g_whh[g]; pa.wih[g] = g_wih[g];
    pa.bih[g] = g_bih[g]; pa.bhh[g] = g_bhh[g];
    pa.waug[g] = waug[g];
    pa.src[g][0] = fcw[g][0]; pa.dst[g][0] = w1b[g];
    pa.src[g][1] = fcw[g][1]; pa.dst[g][1] = w2b[g];
    pa.src[g][2] = fcw[g][2]; pa.dst[g][2] = w3b[g];
    pa.src[g][3] = fcw[g][3]; pa.dst[g][3] = w4b[g];
    pa.qb[g] = qb[g];
  }
  pa.out = out;
  prep_kernel<<<dim3(64, 11), 256, 0, stream>>>(pa);

  (void)hipFuncSetAttribute((const void*)gru_kernel,
                            hipFuncAttributeMaxDynamicSharedMemorySize,
                            GRU_LDS_BYTES);
  gru_kernel<<<dim3(256), dim3(256), GRU_LDS_BYTES, stream>>>(
      state, action, lengths, waug[0], waug[1], g_bhh[0], g_bhh[1], xb[0], xb[1]);

  gemm_dbuf<<<dim3(32, 16, 2), 256, 0, stream>>>(
      xb[0], xb[1], w1b[0], w1b[1], fcb[0][0], fcb[1][0], yA[0], yA[1], 1024, 320);
  gemm_dbuf<<<dim3(32, 16, 2), 256, 0, stream>>>(
      yA[0], yA[1], w2b[0], w2b[1], fcb[0][1], fcb[1][1], yB[0], yB[1], 1024, 1024);
  gemm_dbuf<<<dim3(32, 8, 2), 256, 0, stream>>>(
      yB[0], yB[1], w3b[0], w3b[1], fcb[0][2], fcb[1][2], yA[0], yA[1], 512, 1024);
  fc4q_kernel<<<dim3(64, 2, 2), 256, 0, stream>>>(
      yA[0], yA[1], w4b[0], w4b[1], fcb[0][3], fcb[1][3], qw[0], qw[1], out);
}

// Round 9
// 339.023 us; speedup vs baseline: 1.0642x; 1.0642x over previous
//
#include <hip/hip_runtime.h>

// ---------- types ----------
typedef float  f32x4 __attribute__((ext_vector_type(4)));
typedef short  s16x8 __attribute__((ext_vector_type(8)));
typedef __bf16 b16x8 __attribute__((ext_vector_type(8)));

#define DEV __device__ __forceinline__

DEV unsigned short f2b(float f) {           // fp32 -> bf16 RNE
  unsigned u = __builtin_bit_cast(unsigned, f);
  u = (u + 0x7FFFu + ((u >> 16) & 1u)) >> 16;
  return (unsigned short)u;
}
DEV b16x8 ld8(const unsigned short* p) {    // 16B fragment load + reinterpret
  return __builtin_bit_cast(b16x8, *(const s16x8*)p);
}
DEV float sigm(float x) { return __builtin_amdgcn_rcpf(1.f + __expf(-x)); }
DEV float tanh_fast(float x) {
  float e = __expf(2.f * x);                // overflow-safe: e=inf -> 1, e=0 -> -1
  return 1.f - 2.f * __builtin_amdgcn_rcpf(e + 1.f);
}
DEV void async16(const unsigned short* g, unsigned short* l) {
  __builtin_amdgcn_global_load_lds(
      (const __attribute__((address_space(1))) unsigned int*)g,
      (__attribute__((address_space(3))) unsigned int*)l, 16, 0, 0);
}
DEV f32x4 mfma_bf16(b16x8 a, b16x8 b, f32x4 c) {
  return __builtin_amdgcn_mfma_f32_16x16x32_bf16(a, b, c, 0, 0, 0);
}

// ---------- prep: fp32->bf16 weights + PLAIN Waug build + out prefill ----------
// Waug [768][288] = [Whh | Wih | 0] (no perm, no bias fold — R2 GRU adds biases
// via registers). fc1 weights padded to K=320.
struct PrepArgs {
  const float *whh[2], *wih[2];
  const float *src[2][4];               // fc1..fc4 fp32 weights per branch
  unsigned short *waug[2], *dst[2][4];  // bf16 outputs
  const float *qb[2];
  float *out;                           // prefill with qb (fc4q atomically adds)
};

__global__ __launch_bounds__(256) void prep_kernel(PrepArgs p) {
  const int job = blockIdx.y;
  const int i0 = blockIdx.x * 256 + threadIdx.x;
  const int stride = gridDim.x * 256;
  if (job < 2) {
    const float* whh = p.whh[job];
    const float* wih = p.wih[job];
    unsigned short* dst = p.waug[job];
    for (int idx = i0; idx < 768 * 288; idx += stride) {
      int j = idx / 288, k = idx - j * 288;
      float v = 0.f;
      if (k < 256)      v = whh[j * 256 + k];
      else if (k < 271) v = wih[j * 15 + (k - 256)];
      dst[idx] = f2b(v);
    }
  } else if (job < 10) {
    const int jj = job - 2, br = jj >> 2, ly = jj & 3;
    const int rowsA[4] = {1024, 1024, 512, 256};
    const int scA[4]   = {272, 1024, 1024, 512};
    const int dcA[4]   = {320, 1024, 1024, 512};   // fc1 K padded to 320
    const float* src = p.src[br][ly];
    unsigned short* dst = p.dst[br][ly];
    const int sc = scA[ly], dc = dcA[ly], tot = rowsA[ly] * dc;
    for (int idx = i0; idx < tot; idx += stride) {
      int r = idx / dc, c = idx - r * dc;
      float v = (c < sc) ? src[r * sc + c] : 0.f;
      dst[idx] = f2b(v);
    }
  } else {
    for (int idx = i0; idx < 4096; idx += stride)
      p.out[idx] = p.qb[idx >> 11][0];
  }
}

// ---------- persistent fused GRU — exact R2 structure (measured 152 us) -------
// 256 blocks x 512 thr; block = (gru g, 16 batch rows).
// Waug ksteps {aug,0,1,2} register-resident, {6,7} in per-lane LDS arena,
// {3,4,5} L2-streamed with 1-deep prefetch. Two barriers/step, Hb stride 296.
#define GRU_LDS_BYTES 140672
__global__ __launch_bounds__(512) void gru_kernel(
    const float* __restrict__ state, const float* __restrict__ action,
    const int* __restrict__ lengths,
    const unsigned short* __restrict__ waug0, const unsigned short* __restrict__ waug1,
    const float* __restrict__ bih0, const float* __restrict__ bhh0,
    const float* __restrict__ bih1, const float* __restrict__ bhh1,
    unsigned short* __restrict__ x0, unsigned short* __restrict__ x1) {
  extern __shared__ char smem[];
  unsigned short* W67L = (unsigned short*)smem;             // 96 KB arena (k6,7)
  unsigned short* SgL  = (unsigned short*)(smem + 98304);   // 32 KB state frags
  unsigned short* Hb   = (unsigned short*)(smem + 131072);  // 16 x 296 halves
  int* lenS = (int*)(smem + 140544);
  int* mlS  = (int*)(smem + 140608);
  float* tmpF = (float*)smem;                               // phase-a overlay

  const int tid = threadIdx.x;
  const int lane = tid & 63, w = tid >> 6;
  const int l15 = lane & 15, q = lane >> 4;
  const int g = blockIdx.x & 1;
  const int r0 = (blockIdx.x >> 1) * 16;

  const unsigned short* Waug = g ? waug1 : waug0;
  const float* bih = g ? bih1 : bih0;
  const float* bhh = g ? bhh1 : bhh0;
  unsigned short* xout = g ? x1 : x0;

  // ---- phase a: state tile fp32 -> LDS (coalesced); lens; zero Hb ----
  {
    const float4* src = (const float4*)(state + (size_t)r0 * 960);
    float4* dstv = (float4*)tmpF;
    for (int i = tid; i < 3840; i += 512) dstv[i] = src[i];
  }
  for (int i = tid; i < 16 * 296; i += 512) Hb[i] = 0;
  if (tid < 16) lenS[tid] = lengths[r0 + tid];
  __syncthreads();
  if (tid == 0) {
    int m = 1;
    for (int i = 0; i < 16; i++) m = lenS[i] > m ? lenS[i] : m;
    *mlS = m;
  }

  // ---- phase b: SgL[t][L] = aug A-fragment (state 15 | 1.0 | 0) ----
  for (int s = tid; s < 64 * 32; s += 512) {
    const int t = s >> 5, L = s & 31;
    const int q2 = L >> 4, r = L & 15;
    s16x8 h;
#pragma unroll
    for (int j = 0; j < 8; j++) {
      const int k = q2 * 8 + j;
      float v = (k < 15) ? tmpF[r * 960 + t * 15 + k] : (k == 15 ? 1.0f : 0.f);
      h[j] = (short)f2b(v);
    }
    *(s16x8*)(SgL + (size_t)s * 8) = h;
  }
  __syncthreads();  // tmpF dead; arena may be filled

  // ---- phase c: resident weights + arena fill ----
  int c0[6];
  c0[0] = 32 * w;       c0[1] = 32 * w + 16;
  c0[2] = 256 + 32 * w; c0[3] = 256 + 32 * w + 16;
  c0[4] = 512 + 32 * w; c0[5] = 512 + 32 * w + 16;

  float brz[4];
#pragma unroll
  for (int i = 0; i < 4; i++) brz[i] = bih[c0[i] + l15] + bhh[c0[i] + l15];
  float bnI[2] = {bih[c0[4] + l15], bih[c0[5] + l15]};
  float bnH[2] = {bhh[c0[4] + l15], bhh[c0[5] + l15]};

  const unsigned short* bp[6];
#pragma unroll
  for (int i = 0; i < 6; i++) bp[i] = Waug + (size_t)(c0[i] + l15) * 288 + q * 8;

  // register-resident B-fragments for ksteps {aug(=8), 0, 1, 2}
  b16x8 wres[6][4];
  const int ksmap[4] = {8, 0, 1, 2};
#pragma unroll
  for (int i = 0; i < 6; i++) {
#pragma unroll
    for (int j = 0; j < 4; j++) wres[i][j] = ld8(bp[i] + ksmap[j] * 32);
#pragma unroll
    for (int ks2 = 0; ks2 < 2; ks2++) {
      b16x8 v = ld8(bp[i] + (6 + ks2) * 32);
      *(s16x8*)(W67L + (size_t)(ks2 * 6 + i) * 4096 + tid * 8) =
          __builtin_bit_cast(s16x8, v);
    }
  }
  int len4[4];
#pragma unroll
  for (int r = 0; r < 4; r++) len4[r] = lenS[q * 4 + r];
  __syncthreads();
  const int maxlen = *mlS;

  float hold[2][4] = {{0, 0, 0, 0}, {0, 0, 0, 0}};  // fp32 recurrent carry
  const short qmask = (q < 2) ? (short)-1 : (short)0;
  const s16x8 qm = {qmask, qmask, qmask, qmask, qmask, qmask, qmask, qmask};

  for (int t = 0; t < maxlen; ++t) {
    __syncthreads();  // staging + prev elementwise visible before MFMA reads

    f32x4 acc[6];
#pragma unroll
    for (int i = 0; i < 4; i++) acc[i] = f32x4{brz[i], brz[i], brz[i], brz[i]};
    acc[4] = f32x4{bnI[0], bnI[0], bnI[0], bnI[0]};
    acc[5] = f32x4{bnI[1], bnI[1], bnI[1], bnI[1]};

    // aug kstep first: acc = bih + state@Wih  (== i gates)
    {
      s16x8 raw = *(const s16x8*)(SgL + t * 256 + ((q & 1) * 16 + l15) * 8);
      raw &= qm;
      b16x8 a8 = __builtin_bit_cast(b16x8, raw);
#pragma unroll
      for (int i = 0; i < 6; i++) acc[i] = mfma_bf16(a8, wres[i][0], acc[i]);
    }
    f32x4 giN0 = acc[4], giN1 = acc[5];  // snapshot i_n
    acc[4] = acc[4] + bnH[0];
    acc[5] = acc[5] + bnH[1];

    // resident ksteps 0..2
#pragma unroll
    for (int j = 1; j < 4; j++) {
      b16x8 a = ld8(&Hb[l15 * 296 + (j - 1) * 32 + q * 8]);
#pragma unroll
      for (int i = 0; i < 6; i++) acc[i] = mfma_bf16(a, wres[i][j], acc[i]);
    }

    // streamed ksteps 3..5 (L2-hit), 1-deep prefetch
    b16x8 bs[6];
#pragma unroll
    for (int i = 0; i < 6; i++) bs[i] = ld8(bp[i] + 3 * 32);
#pragma unroll
    for (int ks = 3; ks <= 5; ++ks) {
      b16x8 cur[6];
#pragma unroll
      for (int i = 0; i < 6; i++) cur[i] = bs[i];
      if (ks < 5) {
#pragma unroll
        for (int i = 0; i < 6; i++) bs[i] = ld8(bp[i] + (ks + 1) * 32);
      }
      b16x8 a = ld8(&Hb[l15 * 296 + ks * 32 + q * 8]);
#pragma unroll
      for (int i = 0; i < 6; i++) acc[i] = mfma_bf16(a, cur[i], acc[i]);
    }

    // arena ksteps 6,7 (conflict-free per-lane slots)
#pragma unroll
    for (int ks2 = 0; ks2 < 2; ks2++) {
      b16x8 a = ld8(&Hb[l15 * 296 + (6 + ks2) * 32 + q * 8]);
#pragma unroll
      for (int i = 0; i < 6; i++) {
        b16x8 bw = ld8(W67L + (size_t)(ks2 * 6 + i) * 4096 + tid * 8);
        acc[i] = mfma_bf16(a, bw, acc[i]);
      }
    }

    __syncthreads();  // all waves done reading Hb h-cols before overwrite

    // wave-local elementwise: acc elem = (row=q*4+rg, col=c0[i]+l15)
#pragma unroll
    for (int i = 0; i < 2; i++) {
      const int c = 32 * w + 16 * i + l15;
#pragma unroll
      for (int rg = 0; rg < 4; rg++) {
        const int row = q * 4 + rg;
        float r = sigm(acc[0 + i][rg]);
        float z = sigm(acc[2 + i][rg]);
        float inn = i ? giN1[rg] : giN0[rg];
        float hn = acc[4 + i][rg] - inn;       // h_n = g_n - i_n
        float nn = tanh_fast(inn + r * hn);
        float hv = (1.f - z) * nn + z * hold[i][rg];
        hv = (t < len4[rg]) ? hv : hold[i][rg];  // ragged freeze
        hold[i][rg] = hv;
        Hb[row * 296 + c] = f2b(hv);
      }
    }
  }

  // emit x = [state[:,0,:], action, h, 0-pad] bf16 [16][320]
#pragma unroll
  for (int i = 0; i < 2; i++) {
    const int c = 32 * w + 16 * i + l15;
#pragma unroll
    for (int rg = 0; rg < 4; rg++) {
      const int row = q * 4 + rg;
      xout[(size_t)(r0 + row) * 320 + 16 + c] = f2b(hold[i][rg]);
    }
  }
  for (int s = tid; s < 1024; s += 512) {
    const int row = s >> 6, cc = s & 63;
    float v; int col;
    if (cc < 15)       { v = state[(size_t)(r0 + row) * 960 + cc]; col = cc; }
    else if (cc == 15) { v = action[r0 + row]; col = 15; }
    else               { v = 0.f; col = 256 + cc; }  // 272..319 zero pad
    xout[(size_t)(r0 + row) * 320 + col] = f2b(v);
  }
}

// ---------- bf16 GEMM, reg-staged double-buffer, BK=64, ONE barrier/iter ----
DEV int slotOf(int c) { return (c & ~7) | ((c & 7) ^ ((c >> 3) & 7)); }

__global__ __launch_bounds__(256, 4) void gemm_dbuf(
    const unsigned short* __restrict__ A0, const unsigned short* __restrict__ A1,
    const unsigned short* __restrict__ W0, const unsigned short* __restrict__ W1,
    const float* __restrict__ b0, const float* __restrict__ b1,
    unsigned short* __restrict__ Y0, unsigned short* __restrict__ Y1,
    int N, int K) {
  const unsigned short* A = blockIdx.z ? A1 : A0;
  const unsigned short* W = blockIdx.z ? W1 : W0;
  const float* bias = blockIdx.z ? b1 : b0;
  unsigned short* Y = blockIdx.z ? Y1 : Y0;

  const int tid = threadIdx.x;
  const int lane = tid & 63, wid = tid >> 6;
  const int wm = wid >> 1, wn = wid & 1;
  const int l15 = lane & 15, q = lane >> 4;
  const int m0 = blockIdx.x * 64, n0 = blockIdx.y * 64;

  __shared__ unsigned short As[2][4096];
  __shared__ unsigned short Bs[2][4096];

  f32x4 acc[2][2];
#pragma unroll
  for (int mi = 0; mi < 2; mi++)
#pragma unroll
    for (int ni = 0; ni < 2; ni++) acc[mi][ni] = f32x4{0.f, 0.f, 0.f, 0.f};

  const int c0c = tid * 2, c1c = tid * 2 + 1;
  const int ar0 = c0c >> 3, ak0 = (c0c & 7) * 8;
  const int ar1 = c1c >> 3, ak1 = (c1c & 7) * 8;
  const int ws0 = slotOf(c0c) * 8, ws1 = slotOf(c1c) * 8;
  const unsigned short* pa0 = A + (size_t)(m0 + ar0) * K + ak0;
  const unsigned short* pa1 = A + (size_t)(m0 + ar1) * K + ak1;
  const unsigned short* pb0 = W + (size_t)(n0 + ar0) * K + ak0;
  const unsigned short* pb1 = W + (size_t)(n0 + ar1) * K + ak1;

  const int niter = K >> 6;
  s16x8 ra0 = *(const s16x8*)pa0, ra1 = *(const s16x8*)pa1;
  s16x8 rb0 = *(const s16x8*)pb0, rb1 = *(const s16x8*)pb1;
  *(s16x8*)&As[0][ws0] = ra0; *(s16x8*)&As[0][ws1] = ra1;
  *(s16x8*)&Bs[0][ws0] = rb0; *(s16x8*)&Bs[0][ws1] = rb1;

  for (int it = 0; it < niter; ++it) {
    const unsigned short* as = As[it & 1];
    const unsigned short* bs = Bs[it & 1];
    const bool pf = (it + 1 < niter);
    if (pf) {
      const int k0 = (it + 1) << 6;
      ra0 = *(const s16x8*)(pa0 + k0); ra1 = *(const s16x8*)(pa1 + k0);
      rb0 = *(const s16x8*)(pb0 + k0); rb1 = *(const s16x8*)(pb1 + k0);
    }
    __syncthreads();   // buf[it&1] writes visible to all waves

#pragma unroll
    for (int s = 0; s < 2; s++) {
      b16x8 af[2], bf[2];
#pragma unroll
      for (int mi = 0; mi < 2; mi++) {
        const int ml = wm * 32 + mi * 16 + l15;
        af[mi] = ld8(as + slotOf(ml * 8 + s * 4 + q) * 8);
      }
#pragma unroll
      for (int ni = 0; ni < 2; ni++) {
        const int nl = wn * 32 + ni * 16 + l15;
        bf[ni] = ld8(bs + slotOf(nl * 8 + s * 4 + q) * 8);
      }
#pragma unroll
      for (int mi = 0; mi < 2; mi++)
#pragma unroll
        for (int ni = 0; ni < 2; ni++)
          acc[mi][ni] = mfma_bf16(af[mi], bf[ni], acc[mi][ni]);
    }
    if (pf) {
      const int nb = (it + 1) & 1;
      *(s16x8*)&As[nb][ws0] = ra0; *(s16x8*)&As[nb][ws1] = ra1;
      *(s16x8*)&Bs[nb][ws0] = rb0; *(s16x8*)&Bs[nb][ws1] = rb1;
    }
  }

#pragma unroll
  for (int ni = 0; ni < 2; ni++) {
    const int col = n0 + wn * 32 + ni * 16 + l15;
    const float bv = bias[col];
#pragma unroll
    for (int mi = 0; mi < 2; mi++) {
      const int rbase = m0 + wm * 32 + mi * 16 + q * 4;
#pragma unroll
      for (int rg = 0; rg < 4; rg++) {
        float v = acc[mi][ni][rg] + bv;
        v = fmaxf(v, 0.f);
        Y[(size_t)(rbase + rg) * N + col] = f2b(v);
      }
    }
  }
}

// ---------- fc4 + q fused: out[b] += qw . relu(y3[b] @ W4^T + b4) ----------
__global__ __launch_bounds__(256, 4) void fc4q_kernel(
    const unsigned short* __restrict__ A0, const unsigned short* __restrict__ A1,
    const unsigned short* __restrict__ W0, const unsigned short* __restrict__ W1,
    const float* __restrict__ b0, const float* __restrict__ b1,
    const float* __restrict__ qw0, const float* __restrict__ qw1,
    float* __restrict__ out) {
  const unsigned short* A = blockIdx.z ? A1 : A0;
  const unsigned short* W = blockIdx.z ? W1 : W0;
  const float* bias = blockIdx.z ? b1 : b0;
  const float* qw = blockIdx.z ? qw1 : qw0;

  const int tid = threadIdx.x;
  const int lane = tid & 63, wn = tid >> 6;
  const int l15 = lane & 15, q = lane >> 4;
  const int m0 = blockIdx.x * 32;
  const int nbase = blockIdx.y * 128;
  const int K = 512;

  __shared__ unsigned short As[32 * 32];
  __shared__ unsigned short Bs[128 * 32];
  __shared__ float red[32][4];

  f32x4 acc[2][2];
#pragma unroll
  for (int mi = 0; mi < 2; mi++)
#pragma unroll
    for (int ni = 0; ni < 2; ni++) acc[mi][ni] = f32x4{0.f, 0.f, 0.f, 0.f};

  const int srow = tid >> 2, scol = (tid & 3) * 8;
  for (int k0 = 0; k0 < K; k0 += 32) {
    if (tid < 128)
      async16(A + (size_t)(m0 + srow) * K + scol + k0, &As[tid * 8]);
#pragma unroll
    for (int g64 = 0; g64 < 2; g64++)
      async16(W + (size_t)(nbase + g64 * 64 + srow) * K + scol + k0,
              &Bs[g64 * 2048 + tid * 8]);
    __syncthreads();

    b16x8 af[2], bf[2];
#pragma unroll
    for (int mi = 0; mi < 2; mi++)
      af[mi] = ld8(&As[(mi * 16 + l15) * 32 + q * 8]);
#pragma unroll
    for (int ni = 0; ni < 2; ni++)
      bf[ni] = ld8(&Bs[(wn * 32 + ni * 16 + l15) * 32 + q * 8]);
#pragma unroll
    for (int mi = 0; mi < 2; mi++)
#pragma unroll
      for (int ni = 0; ni < 2; ni++)
        acc[mi][ni] = mfma_bf16(af[mi], bf[ni], acc[mi][ni]);
    __syncthreads();
  }

#pragma unroll
  for (int mi = 0; mi < 2; mi++) {
#pragma unroll
    for (int rg = 0; rg < 4; rg++) {
      float s = 0.f;
#pragma unroll
      for (int ni = 0; ni < 2; ni++) {
        const int col = nbase + wn * 32 + ni * 16 + l15;
        float v = fmaxf(acc[mi][ni][rg] + bias[col], 0.f);
        s += v * qw[col];
      }
#pragma unroll
      for (int off = 1; off < 16; off <<= 1) s += __shfl_xor(s, off);
      if (l15 == 0) red[mi * 16 + q * 4 + rg][wn] = s;
    }
  }
  __syncthreads();
  if (tid < 32) {
    float t = red[tid][0] + red[tid][1] + red[tid][2] + red[tid][3];
    atomicAdd(out + (size_t)blockIdx.z * 2048 + m0 + tid, t);
  }
}

// ---------- host ----------
extern "C" void kernel_launch(void* const* d_in, const int* in_sizes, int n_in,
                              void* d_out, int out_size, void* d_ws, size_t ws_size,
                              hipStream_t stream) {
  const float* state   = (const float*)d_in[0];
  const float* action  = (const float*)d_in[1];
  const int*   lengths = (const int*)d_in[2];
  const float* g_wih[2] = {(const float*)d_in[3], (const float*)d_in[17]};
  const float* g_whh[2] = {(const float*)d_in[4], (const float*)d_in[18]};
  const float* g_bih[2] = {(const float*)d_in[5], (const float*)d_in[19]};
  const float* g_bhh[2] = {(const float*)d_in[6], (const float*)d_in[20]};
  const float* fcw[2][4] = {
      {(const float*)d_in[7], (const float*)d_in[9], (const float*)d_in[11], (const float*)d_in[13]},
      {(const float*)d_in[21], (const float*)d_in[23], (const float*)d_in[25], (const float*)d_in[27]}};
  const float* fcb[2][4] = {
      {(const float*)d_in[8], (const float*)d_in[10], (const float*)d_in[12], (const float*)d_in[14]},
      {(const float*)d_in[22], (const float*)d_in[24], (const float*)d_in[26], (const float*)d_in[28]}};
  const float* qw[2] = {(const float*)d_in[15], (const float*)d_in[29]};
  const float* qb[2] = {(const float*)d_in[16], (const float*)d_in[30]};
  float* out = (float*)d_out;

  uintptr_t base = (uintptr_t)d_ws;
  auto alloc = [&](size_t bytes) -> unsigned short* {
    void* p = (void*)base;
    base += (bytes + 255) & ~(size_t)255;
    return (unsigned short*)p;
  };
  unsigned short *waug[2], *w1b[2], *w2b[2], *w3b[2], *w4b[2], *xb[2], *yA[2], *yB[2];
  for (int g = 0; g < 2; g++) waug[g] = alloc(768 * 288 * 2);
  for (int g = 0; g < 2; g++) w1b[g] = alloc(1024 * 320 * 2);
  for (int g = 0; g < 2; g++) w2b[g] = alloc(1024 * 1024 * 2);
  for (int g = 0; g < 2; g++) w3b[g] = alloc(512 * 1024 * 2);
  for (int g = 0; g < 2; g++) w4b[g] = alloc(256 * 512 * 2);
  for (int g = 0; g < 2; g++) xb[g] = alloc(2048 * 320 * 2);
  for (int g = 0; g < 2; g++) yA[g] = alloc(2048 * 1024 * 2);
  for (int g = 0; g < 2; g++) yB[g] = alloc(2048 * 1024 * 2);
  (void)ws_size; (void)in_sizes; (void)n_in; (void)out_size;

  PrepArgs pa;
  for (int g = 0; g < 2; g++) {
    pa.whh[g] = g_whh[g]; pa.wih[g] = g_wih[g];
    pa.waug[g] = waug[g];
    pa.src[g][0] = fcw[g][0]; pa.dst[g][0] = w1b[g];
    pa.src[g][1] = fcw[g][1]; pa.dst[g][1] = w2b[g];
    pa.src[g][2] = fcw[g][2]; pa.dst[g][2] = w3b[g];
    pa.src[g][3] = fcw[g][3]; pa.dst[g][3] = w4b[g];
    pa.qb[g] = qb[g];
  }
  pa.out = out;
  prep_kernel<<<dim3(64, 11), 256, 0, stream>>>(pa);

  (void)hipFuncSetAttribute((const void*)gru_kernel,
                            hipFuncAttributeMaxDynamicSharedMemorySize,
                            GRU_LDS_BYTES);
  gru_kernel<<<dim3(256), dim3(512), GRU_LDS_BYTES, stream>>>(
      state, action, lengths, waug[0], waug[1],
      g_bih[0], g_bhh[0], g_bih[1], g_bhh[1], xb[0], xb[1]);

  gemm_dbuf<<<dim3(32, 16, 2), 256, 0, stream>>>(
      xb[0], xb[1], w1b[0], w1b[1], fcb[0][0], fcb[1][0], yA[0], yA[1], 1024, 320);
  gemm_dbuf<<<dim3(32, 16, 2), 256, 0, stream>>>(
      yA[0], yA[1], w2b[0], w2b[1], fcb[0][1], fcb[1][1], yB[0], yB[1], 1024, 1024);
  gemm_dbuf<<<dim3(32, 8, 2), 256, 0, stream>>>(
      yB[0], yB[1], w3b[0], w3b[1], fcb[0][2], fcb[1][2], yA[0], yA[1], 512, 1024);
  fc4q_kernel<<<dim3(64, 2, 2), 256, 0, stream>>>(
      yA[0], yA[1], w4b[0], w4b[1], fcb[0][3], fcb[1][3], qw[0], qw[1], out);
}